// Round 3
// baseline (3704.628 us; speedup 1.0000x reference)
//
#include <hip/hip_runtime.h>
#include <cstdint>
#include <cfloat>
#include <climits>

#define NPTS 20000
#define NB 4
#define MP 1024
#define CF 512
#define MAXP 20          // max compacted points per thread (worst case all masked)

__constant__ float c_r2[4]  = { (float)(0.025*0.025), (float)(0.05*0.05),
                                (float)(0.075*0.075), (float)(0.1*0.1) };
__constant__ float c_rad[4] = { 0.025f, 0.05f, 0.075f, 0.1f };

// ---------------------------------------------------------------------------
// K1: masked FPS over the COMPACTED masked point set, one block per batch.
// Masked-out points are constant -BIG in the reference and can never win the
// argmax, so scanning only masked points is bit-exact (order-preserving
// compaction keeps the first-max tie-break identical). Typical K ~= 9000
// -> 9 pts/thread: xyz arrays fit registers even at a 64-VGPR allocation.
// dist lives in LDS. Exact numerics: rn ops, no FMA contraction.
// ---------------------------------------------------------------------------
__global__ __launch_bounds__(1024)
void k_fps(const float* __restrict__ xyz, const float* __restrict__ obj,
           const float* __restrict__ grasp, int* __restrict__ idxs,
           float* __restrict__ xyz_g,
           float* __restrict__ xc, float* __restrict__ yc,
           float* __restrict__ zc, int* __restrict__ ci)
{
    const int b = blockIdx.x;
    const int tid = threadIdx.x;
    const int lane = tid & 63, wid = tid >> 6;
    const float* xb  = xyz   + (size_t)b * NPTS * 3;
    const float* ob0 = obj   + (size_t)b * 2 * NPTS;
    const float* ob1 = ob0 + NPTS;
    const float* gb  = grasp + (size_t)b * NPTS;
    float* xcb = xc + (size_t)b * 20480;
    float* ycb = yc + (size_t)b * 20480;
    float* zcb = zc + (size_t)b * 20480;
    int*   cib = ci + (size_t)b * 20480;

    __shared__ float sDist[MAXP * MP];                 // 80 KB
    __shared__ int   sWaveCnt[16];
    __shared__ unsigned long long sKey[2][16];
    __shared__ float sX[2][16], sY[2][16], sZ[2][16];
    __shared__ int   s_sel[MP];

    // ---- phase A: order-preserving compaction of masked points ----
    int kbase = 0;
    for (int i = 0; i < MAXP; ++i) {
        int n = i * MP + tid;
        bool msk = false; float x = 0.f, y = 0.f, z = 0.f;
        if (n < NPTS) {
            msk = (ob1[n] > ob0[n]) && (gb[n] > 0.1f);
            if (msk) { x = xb[n*3+0]; y = xb[n*3+1]; z = xb[n*3+2]; }
        }
        unsigned long long bal = __ballot(msk);
        if (lane == 0) sWaveCnt[wid] = __popcll(bal);
        __syncthreads();
        int pre = 0, tot = 0;
        for (int w = 0; w < 16; ++w) { int c = sWaveCnt[w]; tot += c; if (w < wid) pre += c; }
        if (msk) {
            int rank = kbase + pre + __popcll(bal & ((1ull << lane) - 1ull));
            xcb[rank] = x; ycb[rank] = y; zcb[rank] = z; cib[rank] = n;
        }
        kbase += tot;
        __syncthreads();
    }
    const int K = kbase;                 // uniform across block

    if (K == 0) {                        // ref: argmax of all-equal -> index 0 forever
        idxs[b*MP + tid] = 0;
        xyz_g[((size_t)b*MP + tid)*3 + 0] = xb[0];
        xyz_g[((size_t)b*MP + tid)*3 + 1] = xb[1];
        xyz_g[((size_t)b*MP + tid)*3 + 2] = xb[2];
        return;
    }
    const int P = (K + MP - 1) >> 10;    // compacted points per thread

    // ---- phase B: load this thread's compacted points into registers ----
    float px[MAXP], py[MAXP], pz[MAXP];
#pragma unroll
    for (int i = 0; i < MAXP; ++i) {
        if (i >= P) break;
        int c = tid + (i << 10);
        if (c < K) {
            px[i] = xcb[c]; py[i] = ycb[c]; pz[i] = zcb[c];
            sDist[c] = 1e10f;
        } else {
            px[i] = 0.f; py[i] = 0.f; pz[i] = 0.f;
            sDist[c] = -3.0e38f;
        }
    }
    // first pick = first masked original index = compacted position 0
    float lx = xcb[0], ly = ycb[0], lz = zcb[0];
    if (tid == 0) s_sel[0] = 0;
    __syncthreads();

    // ---- phase C: 1023 sequential FPS iterations ----
    for (int it = 1; it < MP; ++it) {
        float bv = -3.4e38f; int bn = 0;
        float bx = 0.f, byy = 0.f, bz = 0.f;
#pragma unroll
        for (int i = 0; i < MAXP; ++i) {
            if (i >= P) break;
            int c = tid + (i << 10);
            float old = sDist[c];
            float dx = px[i] - lx, dy = py[i] - ly, dz = pz[i] - lz;
            float d = __fadd_rn(__fadd_rn(__fmul_rn(dx,dx), __fmul_rn(dy,dy)),
                                __fmul_rn(dz,dz));
            float nd = fminf(old, d);
            sDist[c] = nd;
            bool w = nd > bv;
            bn = w ? c : bn; bx = w ? px[i] : bx;
            byy = w ? py[i] : byy; bz = w ? pz[i] : bz;
            bv = fmaxf(bv, nd);
        }
        // orderable key: max value, then min compacted index (== np.argmax)
        unsigned int ob = __float_as_uint(bv);
        unsigned int ord = (ob & 0x80000000u) ? ~ob : (ob | 0x80000000u);
        unsigned long long key = ((unsigned long long)ord << 32)
                               | (unsigned int)(~bn);
#pragma unroll
        for (int off = 1; off < 64; off <<= 1) {
            unsigned long long ok = __shfl_xor(key, off);
            float ox = __shfl_xor(bx, off), oy = __shfl_xor(byy, off), oz = __shfl_xor(bz, off);
            if (ok > key) { key = ok; bx = ox; byy = oy; bz = oz; }
        }
        int p = it & 1;
        if (lane == 0) { sKey[p][wid] = key; sX[p][wid] = bx; sY[p][wid] = byy; sZ[p][wid] = bz; }
        __syncthreads();
        int j = lane & 15;
        unsigned long long k2 = sKey[p][j];
        float x2 = sX[p][j], y2 = sY[p][j], z2 = sZ[p][j];
#pragma unroll
        for (int off = 1; off < 16; off <<= 1) {
            unsigned long long ok = __shfl_xor(k2, off);
            float ox = __shfl_xor(x2, off), oy = __shfl_xor(y2, off), oz = __shfl_xor(z2, off);
            if (ok > k2) { k2 = ok; x2 = ox; y2 = oy; z2 = oz; }
        }
        int n = ~((unsigned int)k2);
        lx = x2; ly = y2; lz = z2;
        if (tid == 0) s_sel[it] = n;
    }
    __syncthreads();
    int nc = s_sel[tid];
    idxs[b*MP + tid] = cib[nc];
    xyz_g[((size_t)b*MP + tid)*3 + 0] = xcb[nc];
    xyz_g[((size_t)b*MP + tid)*3 + 1] = ycb[nc];
    xyz_g[((size_t)b*MP + tid)*3 + 2] = zcb[nc];
}

// ---------------------------------------------------------------------------
// K2: gather feat_g[b,m,c] = seed_features[b,c,idx[m]]
// ---------------------------------------------------------------------------
__global__ void k_gather_feat(const float* __restrict__ sf, const int* __restrict__ idxs,
                              float* __restrict__ feat_g)
{
    int bm = blockIdx.x;
    int b = bm >> 10;
    int n = idxs[bm];
    const float* src = sf + (size_t)b*CF*NPTS + n;
    float* dst = feat_g + (size_t)bm*CF;
    for (int c = threadIdx.x; c < CF; c += 256) dst[c] = src[(size_t)c * NPTS];
}

// ---------------------------------------------------------------------------
// K3b: small prep - transpose w2 -> w2t[k][c][o], extract w1 xyz cols
// ---------------------------------------------------------------------------
__global__ void k_prep(const float* __restrict__ w1, const float* __restrict__ w2,
                       float* __restrict__ w2t, float* __restrict__ w1x)
{
    int k = blockIdx.x, cb = blockIdx.y*32, ob = blockIdx.z*32;
    int tx = threadIdx.x & 31, ty = threadIdx.x >> 5;
    __shared__ float t[32][33];
    for (int r = ty; r < 32; r += 8)
        t[r][tx] = w2[((size_t)k*256 + ob + r)*256 + cb + tx];
    __syncthreads();
    for (int r = ty; r < 32; r += 8)
        w2t[((size_t)k*256 + cb + r)*256 + ob + tx] = t[tx][r];
    if (blockIdx.y == 0 && blockIdx.z == 0) {
        int o = threadIdx.x;
        for (int d = 0; d < 3; ++d)
            w1x[(k*3 + d)*256 + o] = w1[((size_t)k*256 + o)*515 + d];
    }
}

// ---------------------------------------------------------------------------
// K3: F1[k][b*1024+n][o] = feat_g[b,n,:] . w1[k][o][3:] + b1[k][o]
// ---------------------------------------------------------------------------
__global__ __launch_bounds__(256)
void k_f1(const float* __restrict__ feat_g, const float* __restrict__ w1,
          const float* __restrict__ b1, float* __restrict__ F1)
{
    const int rt = blockIdx.x * 64;
    const int ot = blockIdx.y * 64;
    const int k  = blockIdx.z;
    const int tid = threadIdx.x;
    __shared__ float As[16][68];
    __shared__ float Bs[16][68];
    const int lr = tid >> 2;
    const int lc = (tid & 3) * 4;
    const int tr = (tid & 15) * 4;
    const int tc = (tid >> 4) * 4;
    float acc[4][4] = {};
    for (int kk = 0; kk < CF; kk += 16) {
        const float* ap = feat_g + (size_t)(rt + lr)*CF + kk + lc;
        As[lc+0][lr] = ap[0]; As[lc+1][lr] = ap[1];
        As[lc+2][lr] = ap[2]; As[lc+3][lr] = ap[3];
        const float* bp = w1 + (size_t)(k*256 + ot + lr)*515 + 3 + kk + lc;
        Bs[lc+0][lr] = bp[0]; Bs[lc+1][lr] = bp[1];
        Bs[lc+2][lr] = bp[2]; Bs[lc+3][lr] = bp[3];
        __syncthreads();
#pragma unroll
        for (int cc = 0; cc < 16; ++cc) {
            float a0=As[cc][tr+0], a1=As[cc][tr+1], a2=As[cc][tr+2], a3=As[cc][tr+3];
            float q0=Bs[cc][tc+0], q1=Bs[cc][tc+1], q2=Bs[cc][tc+2], q3=Bs[cc][tc+3];
            acc[0][0]+=a0*q0; acc[0][1]+=a0*q1; acc[0][2]+=a0*q2; acc[0][3]+=a0*q3;
            acc[1][0]+=a1*q0; acc[1][1]+=a1*q1; acc[1][2]+=a1*q2; acc[1][3]+=a1*q3;
            acc[2][0]+=a2*q0; acc[2][1]+=a2*q1; acc[2][2]+=a2*q2; acc[2][3]+=a2*q3;
            acc[3][0]+=a3*q0; acc[3][1]+=a3*q1; acc[3][2]+=a3*q2; acc[3][3]+=a3*q3;
        }
        __syncthreads();
    }
#pragma unroll
    for (int i = 0; i < 4; ++i)
#pragma unroll
        for (int j = 0; j < 4; ++j)
            F1[((size_t)k*4096 + rt+tr+i)*256 + ot+tc+j] = acc[i][j] + b1[k*256 + ot+tc+j];
}

// ---------------------------------------------------------------------------
// K4: cylinder neighbor query, one block per (b,m), thread = candidate n
// ---------------------------------------------------------------------------
__global__ __launch_bounds__(1024)
void k_nbr(const float* __restrict__ xyz_g, const float* __restrict__ rot,
           int* __restrict__ sel, float* __restrict__ lxyz, int* __restrict__ cnt)
{
    const int bm = blockIdx.x;
    const int b = bm >> 10;
    const int tid = threadIdx.x;
    const int lane = tid & 63, wid = tid >> 6;
    __shared__ float sR[9], sC[3];
    __shared__ int   sSel[4][16];
    __shared__ float sL[4][16][3];
    __shared__ int   sW[16];
    __shared__ int   sCnt[4];
    __shared__ float sFb[3];
    if (tid < 9) sR[tid] = rot[(size_t)bm*9 + tid];
    if (tid < 3) sC[tid] = xyz_g[(size_t)bm*3 + tid];
    __syncthreads();
    float x = xyz_g[((size_t)b*MP + tid)*3 + 0];
    float y = xyz_g[((size_t)b*MP + tid)*3 + 1];
    float z = xyz_g[((size_t)b*MP + tid)*3 + 2];
    float dx = x - sC[0], dy = y - sC[1], dz = z - sC[2];
    float l0 = __fadd_rn(__fadd_rn(__fmul_rn(dx,sR[0]), __fmul_rn(dy,sR[3])), __fmul_rn(dz,sR[6]));
    float l1 = __fadd_rn(__fadd_rn(__fmul_rn(dx,sR[1]), __fmul_rn(dy,sR[4])), __fmul_rn(dz,sR[7]));
    float l2 = __fadd_rn(__fadd_rn(__fmul_rn(dx,sR[2]), __fmul_rn(dy,sR[5])), __fmul_rn(dz,sR[8]));
    float r2 = __fadd_rn(__fmul_rn(l1,l1), __fmul_rn(l2,l2));
    bool basec = (l0 > -0.02f) && (l0 < 0.04f);
    if (tid == 0) { sFb[0]=l0; sFb[1]=l1; sFb[2]=l2; }
    for (int k = 0; k < 4; ++k) {
        bool c = basec && (r2 < c_r2[k]);
        unsigned long long bal = __ballot(c);
        if (lane == 0) sW[wid] = __popcll(bal);
        __syncthreads();
        int pre = 0, tot = 0;
        for (int w = 0; w < 16; ++w) { int cw = sW[w]; tot += cw; if (w < wid) pre += cw; }
        int rank = pre + __popcll(bal & ((1ull << lane) - 1ull));
        if (c && rank < 16) {
            sSel[k][rank] = tid;
            sL[k][rank][0] = l0; sL[k][rank][1] = l1; sL[k][rank][2] = l2;
        }
        if (tid == 0) sCnt[k] = min(tot, 16);
        __syncthreads();
    }
    if (tid < 64) {
        int k = tid >> 4, j = tid & 15;
        int ck = sCnt[k];
        int src = (j < ck) ? j : 0;
        int v; float a0, a1, a2;
        if (ck > 0) { v = sSel[k][src]; a0=sL[k][src][0]; a1=sL[k][src][1]; a2=sL[k][src][2]; }
        else        { v = 0; a0=sFb[0]; a1=sFb[1]; a2=sFb[2]; }
        size_t off = ((size_t)bm*4 + k)*16 + j;
        sel[off] = v;
        lxyz[off*3+0]=a0; lxyz[off*3+1]=a1; lxyz[off*3+2]=a2;
        if (j == 0) cnt[bm*4 + k] = (ck > 0) ? ck : 1;
    }
}

// ---------------------------------------------------------------------------
// K5: per-task MLP (layer1 via F1 gather + xyz part, layer2 + relu + max)
// ---------------------------------------------------------------------------
__global__ __launch_bounds__(256)
void k_mlp(const float* __restrict__ F1, const float* __restrict__ w1x,
           const float* __restrict__ w2t, const float* __restrict__ b2,
           const int* __restrict__ sel, const float* __restrict__ lxyz,
           const int* __restrict__ cnt, float* __restrict__ cat)
{
    const int gid = blockIdx.x;       // 1024 groups * 4 k
    const int k = gid & 3;
    const int g0 = (gid >> 2) * 4;    // bm base (groups never straddle a batch)
    const int o = threadIdx.x;
    __shared__ float h1s[64][256];    // 64 KB
    int u0 = cnt[(g0+0)*4 + k], u1 = cnt[(g0+1)*4 + k],
        u2 = cnt[(g0+2)*4 + k], u3 = cnt[(g0+3)*4 + k];
    int off1 = u0, off2 = u0+u1, off3 = off2+u2, tot = off3+u3;
    const float wx0 = w1x[(k*3+0)*256 + o];
    const float wx1 = w1x[(k*3+1)*256 + o];
    const float wx2 = w1x[(k*3+2)*256 + o];
    const float rad = c_rad[k];
    const int bbase = (g0 >> 10) * MP;
    for (int r = 0; r < tot; ++r) {
        int t = (r >= off1) + (r >= off2) + (r >= off3);
        int toff = (t==0) ? 0 : ((t==1) ? off1 : ((t==2) ? off2 : off3));
        int j = r - toff;
        int bmk = (g0 + t)*4 + k;
        int n = sel[(size_t)bmk*16 + j];
        float lx = lxyz[((size_t)bmk*16 + j)*3 + 0];
        float ly = lxyz[((size_t)bmk*16 + j)*3 + 1];
        float lz = lxyz[((size_t)bmk*16 + j)*3 + 2];
        float v = F1[((size_t)k*4096 + bbase + n)*256 + o];
        v += (lx/rad)*wx0 + (ly/rad)*wx1 + (lz/rad)*wx2;
        h1s[r][o] = fmaxf(v, 0.f);
    }
    __syncthreads();
    const float b2v = b2[k*256 + o];
    float m0=0.f, m1=0.f, m2=0.f, m3=0.f;
    const float* w2c = w2t + (size_t)k*65536 + o;
    for (int base = 0; base < tot; base += 4) {
        int r0 = base;
        int r1 = min(base+1, tot-1);
        int r2 = min(base+2, tot-1);
        int r3 = min(base+3, tot-1);
        float a0=0.f, a1=0.f, a2=0.f, a3=0.f;
        for (int c = 0; c < 256; c += 4) {
            float wA = w2c[(c+0)*256], wB = w2c[(c+1)*256];
            float wC = w2c[(c+2)*256], wD = w2c[(c+3)*256];
            float4 h;
            h = *(const float4*)&h1s[r0][c]; a0 += h.x*wA + h.y*wB + h.z*wC + h.w*wD;
            h = *(const float4*)&h1s[r1][c]; a1 += h.x*wA + h.y*wB + h.z*wC + h.w*wD;
            h = *(const float4*)&h1s[r2][c]; a2 += h.x*wA + h.y*wB + h.z*wC + h.w*wD;
            h = *(const float4*)&h1s[r3][c]; a3 += h.x*wA + h.y*wB + h.z*wC + h.w*wD;
        }
#pragma unroll
        for (int q = 0; q < 4; ++q) {
            int r = base + q;
            if (r < tot) {
                float a = (q==0) ? a0 : ((q==1) ? a1 : ((q==2) ? a2 : a3));
                int t = (r >= off1) + (r >= off2) + (r >= off3);
                float val = fmaxf(a + b2v, 0.f);
                if      (t==0) m0 = fmaxf(m0, val);
                else if (t==1) m1 = fmaxf(m1, val);
                else if (t==2) m2 = fmaxf(m2, val);
                else           m3 = fmaxf(m3, val);
            }
        }
    }
    cat[(size_t)(g0+0)*1024 + k*256 + o] = m0;
    cat[(size_t)(g0+1)*1024 + k*256 + o] = m1;
    cat[(size_t)(g0+2)*1024 + k*256 + o] = m2;
    cat[(size_t)(g0+3)*1024 + k*256 + o] = m3;
}

// ---------------------------------------------------------------------------
// K6: transpose cat[b][m][f] -> catT[b][f][m]
// ---------------------------------------------------------------------------
__global__ void k_transpose(const float* __restrict__ cat, float* __restrict__ catT)
{
    int bt = blockIdx.x;
    int b = bt >> 10;
    int t2 = bt & 1023;
    int mi = (t2 >> 5) * 32, fi = (t2 & 31) * 32;
    int tx = threadIdx.x & 31, ty = threadIdx.x >> 5;
    __shared__ float t[32][33];
    const float* src = cat + (size_t)b * 1048576;
    float* dst = catT + (size_t)b * 1048576;
    for (int r = ty; r < 32; r += 8) t[r][tx] = src[(size_t)(mi + r)*1024 + fi + tx];
    __syncthreads();
    for (int r = ty; r < 32; r += 8) dst[(size_t)(fi + r)*1024 + mi + tx] = t[tx][r];
}

// ---------------------------------------------------------------------------
// K7: fused[b][o][m] = sum_f cat[b][m][f]*fuse_w[o][f] + fuse_b[o]
// ---------------------------------------------------------------------------
__global__ __launch_bounds__(256)
void k_fuse(const float* __restrict__ catT, const float* __restrict__ fw,
            const float* __restrict__ fb, float* __restrict__ out)
{
    const int o0 = blockIdx.x * 4;
    const int b = blockIdx.y;
    const int m = threadIdx.x * 4;
    const float* ct = catT + (size_t)b * 1048576 + m;
    float4 a0 = {0,0,0,0}, a1 = a0, a2 = a0, a3 = a0;
    for (int f = 0; f < 1024; ++f) {
        const float4 cv = *(const float4*)(ct + (size_t)f*1024);
        float w0 = fw[(size_t)(o0+0)*1024 + f];
        float w1 = fw[(size_t)(o0+1)*1024 + f];
        float w2 = fw[(size_t)(o0+2)*1024 + f];
        float w3 = fw[(size_t)(o0+3)*1024 + f];
        a0.x += cv.x*w0; a0.y += cv.y*w0; a0.z += cv.z*w0; a0.w += cv.w*w0;
        a1.x += cv.x*w1; a1.y += cv.y*w1; a1.z += cv.z*w1; a1.w += cv.w*w1;
        a2.x += cv.x*w2; a2.y += cv.y*w2; a2.z += cv.z*w2; a2.w += cv.w*w2;
        a3.x += cv.x*w3; a3.y += cv.y*w3; a3.z += cv.z*w3; a3.w += cv.w*w3;
    }
#pragma unroll
    for (int q = 0; q < 4; ++q) {
        float bb = fb[o0+q];
        float4 r = (q==0) ? a0 : ((q==1) ? a1 : ((q==2) ? a2 : a3));
        r.x += bb; r.y += bb; r.z += bb; r.w += bb;
        *(float4*)&out[((size_t)b*256 + o0 + q)*1024 + m] = r;
    }
}

// ---------------------------------------------------------------------------
extern "C" void kernel_launch(void* const* d_in, const int* in_sizes, int n_in,
                              void* d_out, int out_size, void* d_ws, size_t ws_size,
                              hipStream_t stream)
{
    const float* seed_xyz      = (const float*)d_in[0];
    const float* seed_features = (const float*)d_in[1];
    const float* objectness    = (const float*)d_in[2];
    const float* graspness     = (const float*)d_in[3];
    const float* rot           = (const float*)d_in[4];
    const float* w1            = (const float*)d_in[5];
    const float* b1            = (const float*)d_in[6];
    const float* w2            = (const float*)d_in[7];
    const float* b2            = (const float*)d_in[8];
    const float* fw            = (const float*)d_in[9];
    const float* fb            = (const float*)d_in[10];
    float* out = (float*)d_out;

    char* ws = (char*)d_ws;
    size_t off = 0;
    int*   idxs   = (int*)(ws + off);  off += 16u<<10;            // 16 KB
    float* xyz_g  = (float*)(ws + off); off += 48u<<10;           // 48 KB
    float* feat_g = (float*)(ws + off); off += 8u<<20;            // 8 MB
    float* F1     = (float*)(ws + off); off += 16u<<20;           // 16 MB
    float* w2t    = (float*)(ws + off); off += 1u<<20;            // 1 MB
    float* w1x    = (float*)(ws + off); off += 64u<<10;           // 12 KB used
    int*   sel    = (int*)(ws + off);   off += 1u<<20;            // 1 MB
    int*   cnt    = (int*)(ws + off);   off += 64u<<10;           // 64 KB
    float* lxyz   = (float*)(ws + off); off += 3u<<20;            // 3 MB
    float* cat    = (float*)(ws + off); off += 16u<<20;           // 16 MB
    float* catT   = (float*)(ws + off); off += 16u<<20;           // 16 MB

    // FPS compaction scratch aliases `cat` (first written much later by k_mlp)
    float* xc = cat;
    float* yc = cat + 4*20480;
    float* zc = cat + 8*20480;
    int*   ci = (int*)(cat + 12*20480);

    k_fps<<<NB, 1024, 0, stream>>>(seed_xyz, objectness, graspness, idxs, xyz_g,
                                   xc, yc, zc, ci);
    k_prep<<<dim3(4,8,8), 256, 0, stream>>>(w1, w2, w2t, w1x);
    k_gather_feat<<<NB*MP, 256, 0, stream>>>(seed_features, idxs, feat_g);
    k_f1<<<dim3(64,4,4), 256, 0, stream>>>(feat_g, w1, b1, F1);
    k_nbr<<<NB*MP, 1024, 0, stream>>>(xyz_g, rot, sel, lxyz, cnt);
    k_mlp<<<4096, 256, 0, stream>>>(F1, w1x, w2t, b2, sel, lxyz, cnt, cat);
    k_transpose<<<4096, 256, 0, stream>>>(cat, catT);
    k_fuse<<<dim3(64,4), 256, 0, stream>>>(catT, fw, fb, out);
}

// Round 4
// 2050.199 us; speedup vs baseline: 1.8070x; 1.8070x over previous
//
#include <hip/hip_runtime.h>
#include <cstdint>
#include <cfloat>
#include <climits>

#define NPTS 20000
#define NB 4
#define MP 1024
#define CF 512
#define MAXCH 20         // compaction chunks (20*1024 >= 20000)
#define PFIX 10          // fast-path points per thread (compile-time!)
#define KFAST (PFIX*MP)  // 10240: fast path covers K <= 10240 (K~9000 expected)

__constant__ float c_r2[4]  = { (float)(0.025*0.025), (float)(0.05*0.05),
                                (float)(0.075*0.075), (float)(0.1*0.1) };
__constant__ float c_rad[4] = { 0.025f, 0.05f, 0.075f, 0.1f };

// ---------------------------------------------------------------------------
// K1: masked FPS over the compacted masked point set, one block per batch.
// Fast path: fixed P=10, points+dist in REGISTERS (constant-index full
// unroll -> SROA), compacted xyz mirrored in LDS for the winner fetch.
// Exact numerics: rn ops, no FMA contraction; tie-break = min index.
// ---------------------------------------------------------------------------
__global__ __launch_bounds__(1024, 4)
void k_fps(const float* __restrict__ xyz, const float* __restrict__ obj,
           const float* __restrict__ grasp, int* __restrict__ idxs,
           float* __restrict__ xyz_g,
           float* __restrict__ xc, float* __restrict__ yc,
           float* __restrict__ zc, int* __restrict__ ci)
{
    const int b = blockIdx.x;
    const int tid = threadIdx.x;
    const int lane = tid & 63, wid = tid >> 6;
    const float* xb  = xyz   + (size_t)b * NPTS * 3;
    const float* ob0 = obj   + (size_t)b * 2 * NPTS;
    const float* ob1 = ob0 + NPTS;
    const float* gb  = grasp + (size_t)b * NPTS;
    float* xcb = xc + (size_t)b * 20480;
    float* ycb = yc + (size_t)b * 20480;
    float* zcb = zc + (size_t)b * 20480;
    int*   cib = ci + (size_t)b * 20480;

    __shared__ float sXYZ[3 * KFAST];          // 120 KB: x | y | z mirrors
    __shared__ int   s_sel[MP];                // 4 KB
    __shared__ unsigned long long sKey[2][16];
    __shared__ int   sWaveCnt[16];
    float* sX = sXYZ;
    float* sY = sXYZ + KFAST;
    float* sZ = sXYZ + 2 * KFAST;

    // ---- phase A: order-preserving compaction of masked points ----
    int kbase = 0;
    for (int i = 0; i < MAXCH; ++i) {
        int n = i * MP + tid;
        bool msk = false; float x = 0.f, y = 0.f, z = 0.f;
        if (n < NPTS) {
            msk = (ob1[n] > ob0[n]) && (gb[n] > 0.1f);
            if (msk) { x = xb[n*3+0]; y = xb[n*3+1]; z = xb[n*3+2]; }
        }
        unsigned long long bal = __ballot(msk);
        if (lane == 0) sWaveCnt[wid] = __popcll(bal);
        __syncthreads();
        int pre = 0, tot = 0;
        for (int w = 0; w < 16; ++w) { int c = sWaveCnt[w]; tot += c; if (w < wid) pre += c; }
        if (msk) {
            int rank = kbase + pre + __popcll(bal & ((1ull << lane) - 1ull));
            xcb[rank] = x; ycb[rank] = y; zcb[rank] = z; cib[rank] = n;
            if (rank < KFAST) { sX[rank] = x; sY[rank] = y; sZ[rank] = z; }
        }
        kbase += tot;
        __syncthreads();
    }
    const int K = kbase;                 // uniform across block

    if (K == 0) {                        // ref: argmax of all-equal -> 0 forever
        idxs[b*MP + tid] = 0;
        xyz_g[((size_t)b*MP + tid)*3 + 0] = xb[0];
        xyz_g[((size_t)b*MP + tid)*3 + 1] = xb[1];
        xyz_g[((size_t)b*MP + tid)*3 + 2] = xb[2];
        return;
    }

    if (K <= KFAST) {
        // ================= FAST PATH: fixed P=10, all in registers ==========
        float px[PFIX], py[PFIX], pz[PFIX], pd[PFIX];
#pragma unroll
        for (int i = 0; i < PFIX; ++i) {
            int c = tid + (i << 10);
            bool v = c < K;
            px[i] = v ? sX[c] : 0.f;
            py[i] = v ? sY[c] : 0.f;
            pz[i] = v ? sZ[c] : 0.f;
            pd[i] = v ? 1e10f : -3.0e38f;
        }
        float lx = sX[0], ly = sY[0], lz = sZ[0];
        if (tid == 0) s_sel[0] = 0;

        for (int it = 1; it < MP; ++it) {
            float bv = -3.4e38f; int bn = 0;
#pragma unroll
            for (int i = 0; i < PFIX; ++i) {
                float dx = px[i] - lx, dy = py[i] - ly, dz = pz[i] - lz;
                float d = __fadd_rn(__fadd_rn(__fmul_rn(dx,dx), __fmul_rn(dy,dy)),
                                    __fmul_rn(dz,dz));
                float nd = fminf(pd[i], d);
                pd[i] = nd;
                bool w = nd > bv;
                bn = w ? (tid + (i << 10)) : bn;
                bv = fmaxf(bv, nd);
            }
            unsigned int ob = __float_as_uint(bv);
            unsigned int ord = (ob & 0x80000000u) ? ~ob : (ob | 0x80000000u);
            unsigned long long key = ((unsigned long long)ord << 32)
                                   | (unsigned int)(~bn);
#pragma unroll
            for (int off = 1; off < 64; off <<= 1) {
                unsigned long long ok = __shfl_xor(key, off);
                key = (ok > key) ? ok : key;
            }
            int p = it & 1;
            if (lane == 0) sKey[p][wid] = key;
            __syncthreads();
            unsigned long long k2 = sKey[p][lane & 15];
#pragma unroll
            for (int off = 1; off < 16; off <<= 1) {
                unsigned long long ok = __shfl_xor(k2, off);
                k2 = (ok > k2) ? ok : k2;
            }
            int n = ~((unsigned int)k2);
            lx = sX[n]; ly = sY[n]; lz = sZ[n];   // ~40-cycle LDS broadcast
            if (tid == 0) s_sel[it] = n;
        }
        __syncthreads();
        int nc = s_sel[tid];
        idxs[b*MP + tid] = cib[nc];
        xyz_g[((size_t)b*MP + tid)*3 + 0] = sX[nc];
        xyz_g[((size_t)b*MP + tid)*3 + 1] = sY[nc];
        xyz_g[((size_t)b*MP + tid)*3 + 2] = sZ[nc];
        return;
    }

    // ================= FALLBACK (K > 10240): global reads, LDS dist ========
    {
        float* fD = sXYZ;                 // 30720 floats >= 20000
        for (int c = tid; c < K; c += MP) fD[c] = 1e10f;
        float lx = xcb[0], ly = ycb[0], lz = zcb[0];
        if (tid == 0) s_sel[0] = 0;
        __syncthreads();
        for (int it = 1; it < MP; ++it) {
            float bv = -3.4e38f; int bn = 0;
            for (int c = tid; c < K; c += MP) {
                float dx = xcb[c] - lx, dy = ycb[c] - ly, dz = zcb[c] - lz;
                float d = __fadd_rn(__fadd_rn(__fmul_rn(dx,dx), __fmul_rn(dy,dy)),
                                    __fmul_rn(dz,dz));
                float nd = fminf(fD[c], d);
                fD[c] = nd;
                bool w = nd > bv;
                bn = w ? c : bn;
                bv = fmaxf(bv, nd);
            }
            unsigned int ob = __float_as_uint(bv);
            unsigned int ord = (ob & 0x80000000u) ? ~ob : (ob | 0x80000000u);
            unsigned long long key = ((unsigned long long)ord << 32)
                                   | (unsigned int)(~bn);
#pragma unroll
            for (int off = 1; off < 64; off <<= 1) {
                unsigned long long ok = __shfl_xor(key, off);
                key = (ok > key) ? ok : key;
            }
            int p = it & 1;
            if (lane == 0) sKey[p][wid] = key;
            __syncthreads();
            unsigned long long k2 = sKey[p][lane & 15];
#pragma unroll
            for (int off = 1; off < 16; off <<= 1) {
                unsigned long long ok = __shfl_xor(k2, off);
                k2 = (ok > k2) ? ok : k2;
            }
            int n = ~((unsigned int)k2);
            lx = xcb[n]; ly = ycb[n]; lz = zcb[n];
            if (tid == 0) s_sel[it] = n;
        }
        __syncthreads();
        int nc = s_sel[tid];
        idxs[b*MP + tid] = cib[nc];
        xyz_g[((size_t)b*MP + tid)*3 + 0] = xcb[nc];
        xyz_g[((size_t)b*MP + tid)*3 + 1] = ycb[nc];
        xyz_g[((size_t)b*MP + tid)*3 + 2] = zcb[nc];
    }
}

// ---------------------------------------------------------------------------
// K2: gather feat_g[b,m,c] = seed_features[b,c,idx[m]]
// ---------------------------------------------------------------------------
__global__ void k_gather_feat(const float* __restrict__ sf, const int* __restrict__ idxs,
                              float* __restrict__ feat_g)
{
    int bm = blockIdx.x;
    int b = bm >> 10;
    int n = idxs[bm];
    const float* src = sf + (size_t)b*CF*NPTS + n;
    float* dst = feat_g + (size_t)bm*CF;
    for (int c = threadIdx.x; c < CF; c += 256) dst[c] = src[(size_t)c * NPTS];
}

// ---------------------------------------------------------------------------
// K3b: small prep - transpose w2 -> w2t[k][c][o], extract w1 xyz cols
// ---------------------------------------------------------------------------
__global__ void k_prep(const float* __restrict__ w1, const float* __restrict__ w2,
                       float* __restrict__ w2t, float* __restrict__ w1x)
{
    int k = blockIdx.x, cb = blockIdx.y*32, ob = blockIdx.z*32;
    int tx = threadIdx.x & 31, ty = threadIdx.x >> 5;
    __shared__ float t[32][33];
    for (int r = ty; r < 32; r += 8)
        t[r][tx] = w2[((size_t)k*256 + ob + r)*256 + cb + tx];
    __syncthreads();
    for (int r = ty; r < 32; r += 8)
        w2t[((size_t)k*256 + cb + r)*256 + ob + tx] = t[tx][r];
    if (blockIdx.y == 0 && blockIdx.z == 0) {
        int o = threadIdx.x;
        for (int d = 0; d < 3; ++d)
            w1x[(k*3 + d)*256 + o] = w1[((size_t)k*256 + o)*515 + d];
    }
}

// ---------------------------------------------------------------------------
// K3: F1[k][b*1024+n][o] = feat_g[b,n,:] . w1[k][o][3:] + b1[k][o]
// ---------------------------------------------------------------------------
__global__ __launch_bounds__(256)
void k_f1(const float* __restrict__ feat_g, const float* __restrict__ w1,
          const float* __restrict__ b1, float* __restrict__ F1)
{
    const int rt = blockIdx.x * 64;
    const int ot = blockIdx.y * 64;
    const int k  = blockIdx.z;
    const int tid = threadIdx.x;
    __shared__ float As[16][68];
    __shared__ float Bs[16][68];
    const int lr = tid >> 2;
    const int lc = (tid & 3) * 4;
    const int tr = (tid & 15) * 4;
    const int tc = (tid >> 4) * 4;
    float acc[4][4] = {};
    for (int kk = 0; kk < CF; kk += 16) {
        const float* ap = feat_g + (size_t)(rt + lr)*CF + kk + lc;
        As[lc+0][lr] = ap[0]; As[lc+1][lr] = ap[1];
        As[lc+2][lr] = ap[2]; As[lc+3][lr] = ap[3];
        const float* bp = w1 + (size_t)(k*256 + ot + lr)*515 + 3 + kk + lc;
        Bs[lc+0][lr] = bp[0]; Bs[lc+1][lr] = bp[1];
        Bs[lc+2][lr] = bp[2]; Bs[lc+3][lr] = bp[3];
        __syncthreads();
#pragma unroll
        for (int cc = 0; cc < 16; ++cc) {
            float a0=As[cc][tr+0], a1=As[cc][tr+1], a2=As[cc][tr+2], a3=As[cc][tr+3];
            float q0=Bs[cc][tc+0], q1=Bs[cc][tc+1], q2=Bs[cc][tc+2], q3=Bs[cc][tc+3];
            acc[0][0]+=a0*q0; acc[0][1]+=a0*q1; acc[0][2]+=a0*q2; acc[0][3]+=a0*q3;
            acc[1][0]+=a1*q0; acc[1][1]+=a1*q1; acc[1][2]+=a1*q2; acc[1][3]+=a1*q3;
            acc[2][0]+=a2*q0; acc[2][1]+=a2*q1; acc[2][2]+=a2*q2; acc[2][3]+=a2*q3;
            acc[3][0]+=a3*q0; acc[3][1]+=a3*q1; acc[3][2]+=a3*q2; acc[3][3]+=a3*q3;
        }
        __syncthreads();
    }
#pragma unroll
    for (int i = 0; i < 4; ++i)
#pragma unroll
        for (int j = 0; j < 4; ++j)
            F1[((size_t)k*4096 + rt+tr+i)*256 + ot+tc+j] = acc[i][j] + b1[k*256 + ot+tc+j];
}

// ---------------------------------------------------------------------------
// K4: cylinder neighbor query, one block per (b,m), thread = candidate n
// ---------------------------------------------------------------------------
__global__ __launch_bounds__(1024)
void k_nbr(const float* __restrict__ xyz_g, const float* __restrict__ rot,
           int* __restrict__ sel, float* __restrict__ lxyz, int* __restrict__ cnt)
{
    const int bm = blockIdx.x;
    const int b = bm >> 10;
    const int tid = threadIdx.x;
    const int lane = tid & 63, wid = tid >> 6;
    __shared__ float sR[9], sC[3];
    __shared__ int   sSel[4][16];
    __shared__ float sL[4][16][3];
    __shared__ int   sW[16];
    __shared__ int   sCnt[4];
    __shared__ float sFb[3];
    if (tid < 9) sR[tid] = rot[(size_t)bm*9 + tid];
    if (tid < 3) sC[tid] = xyz_g[(size_t)bm*3 + tid];
    __syncthreads();
    float x = xyz_g[((size_t)b*MP + tid)*3 + 0];
    float y = xyz_g[((size_t)b*MP + tid)*3 + 1];
    float z = xyz_g[((size_t)b*MP + tid)*3 + 2];
    float dx = x - sC[0], dy = y - sC[1], dz = z - sC[2];
    float l0 = __fadd_rn(__fadd_rn(__fmul_rn(dx,sR[0]), __fmul_rn(dy,sR[3])), __fmul_rn(dz,sR[6]));
    float l1 = __fadd_rn(__fadd_rn(__fmul_rn(dx,sR[1]), __fmul_rn(dy,sR[4])), __fmul_rn(dz,sR[7]));
    float l2 = __fadd_rn(__fadd_rn(__fmul_rn(dx,sR[2]), __fmul_rn(dy,sR[5])), __fmul_rn(dz,sR[8]));
    float r2 = __fadd_rn(__fmul_rn(l1,l1), __fmul_rn(l2,l2));
    bool basec = (l0 > -0.02f) && (l0 < 0.04f);
    if (tid == 0) { sFb[0]=l0; sFb[1]=l1; sFb[2]=l2; }
    for (int k = 0; k < 4; ++k) {
        bool c = basec && (r2 < c_r2[k]);
        unsigned long long bal = __ballot(c);
        if (lane == 0) sW[wid] = __popcll(bal);
        __syncthreads();
        int pre = 0, tot = 0;
        for (int w = 0; w < 16; ++w) { int cw = sW[w]; tot += cw; if (w < wid) pre += cw; }
        int rank = pre + __popcll(bal & ((1ull << lane) - 1ull));
        if (c && rank < 16) {
            sSel[k][rank] = tid;
            sL[k][rank][0] = l0; sL[k][rank][1] = l1; sL[k][rank][2] = l2;
        }
        if (tid == 0) sCnt[k] = min(tot, 16);
        __syncthreads();
    }
    if (tid < 64) {
        int k = tid >> 4, j = tid & 15;
        int ck = sCnt[k];
        int src = (j < ck) ? j : 0;
        int v; float a0, a1, a2;
        if (ck > 0) { v = sSel[k][src]; a0=sL[k][src][0]; a1=sL[k][src][1]; a2=sL[k][src][2]; }
        else        { v = 0; a0=sFb[0]; a1=sFb[1]; a2=sFb[2]; }
        size_t off = ((size_t)bm*4 + k)*16 + j;
        sel[off] = v;
        lxyz[off*3+0]=a0; lxyz[off*3+1]=a1; lxyz[off*3+2]=a2;
        if (j == 0) cnt[bm*4 + k] = (ck > 0) ? ck : 1;
    }
}

// ---------------------------------------------------------------------------
// K5: per-task MLP (layer1 via F1 gather + xyz part, layer2 + relu + max)
// ---------------------------------------------------------------------------
__global__ __launch_bounds__(256)
void k_mlp(const float* __restrict__ F1, const float* __restrict__ w1x,
           const float* __restrict__ w2t, const float* __restrict__ b2,
           const int* __restrict__ sel, const float* __restrict__ lxyz,
           const int* __restrict__ cnt, float* __restrict__ cat)
{
    const int gid = blockIdx.x;       // 1024 groups * 4 k
    const int k = gid & 3;
    const int g0 = (gid >> 2) * 4;    // bm base (groups never straddle a batch)
    const int o = threadIdx.x;
    __shared__ float h1s[64][256];    // 64 KB
    int u0 = cnt[(g0+0)*4 + k], u1 = cnt[(g0+1)*4 + k],
        u2 = cnt[(g0+2)*4 + k], u3 = cnt[(g0+3)*4 + k];
    int off1 = u0, off2 = u0+u1, off3 = off2+u2, tot = off3+u3;
    const float wx0 = w1x[(k*3+0)*256 + o];
    const float wx1 = w1x[(k*3+1)*256 + o];
    const float wx2 = w1x[(k*3+2)*256 + o];
    const float rad = c_rad[k];
    const int bbase = (g0 >> 10) * MP;
    for (int r = 0; r < tot; ++r) {
        int t = (r >= off1) + (r >= off2) + (r >= off3);
        int toff = (t==0) ? 0 : ((t==1) ? off1 : ((t==2) ? off2 : off3));
        int j = r - toff;
        int bmk = (g0 + t)*4 + k;
        int n = sel[(size_t)bmk*16 + j];
        float lx = lxyz[((size_t)bmk*16 + j)*3 + 0];
        float ly = lxyz[((size_t)bmk*16 + j)*3 + 1];
        float lz = lxyz[((size_t)bmk*16 + j)*3 + 2];
        float v = F1[((size_t)k*4096 + bbase + n)*256 + o];
        v += (lx/rad)*wx0 + (ly/rad)*wx1 + (lz/rad)*wx2;
        h1s[r][o] = fmaxf(v, 0.f);
    }
    __syncthreads();
    const float b2v = b2[k*256 + o];
    float m0=0.f, m1=0.f, m2=0.f, m3=0.f;
    const float* w2c = w2t + (size_t)k*65536 + o;
    for (int base = 0; base < tot; base += 4) {
        int r0 = base;
        int r1 = min(base+1, tot-1);
        int r2 = min(base+2, tot-1);
        int r3 = min(base+3, tot-1);
        float a0=0.f, a1=0.f, a2=0.f, a3=0.f;
        for (int c = 0; c < 256; c += 4) {
            float wA = w2c[(c+0)*256], wB = w2c[(c+1)*256];
            float wC = w2c[(c+2)*256], wD = w2c[(c+3)*256];
            float4 h;
            h = *(const float4*)&h1s[r0][c]; a0 += h.x*wA + h.y*wB + h.z*wC + h.w*wD;
            h = *(const float4*)&h1s[r1][c]; a1 += h.x*wA + h.y*wB + h.z*wC + h.w*wD;
            h = *(const float4*)&h1s[r2][c]; a2 += h.x*wA + h.y*wB + h.z*wC + h.w*wD;
            h = *(const float4*)&h1s[r3][c]; a3 += h.x*wA + h.y*wB + h.z*wC + h.w*wD;
        }
#pragma unroll
        for (int q = 0; q < 4; ++q) {
            int r = base + q;
            if (r < tot) {
                float a = (q==0) ? a0 : ((q==1) ? a1 : ((q==2) ? a2 : a3));
                int t = (r >= off1) + (r >= off2) + (r >= off3);
                float val = fmaxf(a + b2v, 0.f);
                if      (t==0) m0 = fmaxf(m0, val);
                else if (t==1) m1 = fmaxf(m1, val);
                else if (t==2) m2 = fmaxf(m2, val);
                else           m3 = fmaxf(m3, val);
            }
        }
    }
    cat[(size_t)(g0+0)*1024 + k*256 + o] = m0;
    cat[(size_t)(g0+1)*1024 + k*256 + o] = m1;
    cat[(size_t)(g0+2)*1024 + k*256 + o] = m2;
    cat[(size_t)(g0+3)*1024 + k*256 + o] = m3;
}

// ---------------------------------------------------------------------------
// K6: transpose cat[b][m][f] -> catT[b][f][m]
// ---------------------------------------------------------------------------
__global__ void k_transpose(const float* __restrict__ cat, float* __restrict__ catT)
{
    int bt = blockIdx.x;
    int b = bt >> 10;
    int t2 = bt & 1023;
    int mi = (t2 >> 5) * 32, fi = (t2 & 31) * 32;
    int tx = threadIdx.x & 31, ty = threadIdx.x >> 5;
    __shared__ float t[32][33];
    const float* src = cat + (size_t)b * 1048576;
    float* dst = catT + (size_t)b * 1048576;
    for (int r = ty; r < 32; r += 8) t[r][tx] = src[(size_t)(mi + r)*1024 + fi + tx];
    __syncthreads();
    for (int r = ty; r < 32; r += 8) dst[(size_t)(fi + r)*1024 + mi + tx] = t[tx][r];
}

// ---------------------------------------------------------------------------
// K7: fused[b][o][m] = sum_f cat[b][m][f]*fuse_w[o][f] + fuse_b[o]
// ---------------------------------------------------------------------------
__global__ __launch_bounds__(256)
void k_fuse(const float* __restrict__ catT, const float* __restrict__ fw,
            const float* __restrict__ fb, float* __restrict__ out)
{
    const int o0 = blockIdx.x * 4;
    const int b = blockIdx.y;
    const int m = threadIdx.x * 4;
    const float* ct = catT + (size_t)b * 1048576 + m;
    float4 a0 = {0,0,0,0}, a1 = a0, a2 = a0, a3 = a0;
    for (int f = 0; f < 1024; ++f) {
        const float4 cv = *(const float4*)(ct + (size_t)f*1024);
        float w0 = fw[(size_t)(o0+0)*1024 + f];
        float w1 = fw[(size_t)(o0+1)*1024 + f];
        float w2 = fw[(size_t)(o0+2)*1024 + f];
        float w3 = fw[(size_t)(o0+3)*1024 + f];
        a0.x += cv.x*w0; a0.y += cv.y*w0; a0.z += cv.z*w0; a0.w += cv.w*w0;
        a1.x += cv.x*w1; a1.y += cv.y*w1; a1.z += cv.z*w1; a1.w += cv.w*w1;
        a2.x += cv.x*w2; a2.y += cv.y*w2; a2.z += cv.z*w2; a2.w += cv.w*w2;
        a3.x += cv.x*w3; a3.y += cv.y*w3; a3.z += cv.z*w3; a3.w += cv.w*w3;
    }
#pragma unroll
    for (int q = 0; q < 4; ++q) {
        float bb = fb[o0+q];
        float4 r = (q==0) ? a0 : ((q==1) ? a1 : ((q==2) ? a2 : a3));
        r.x += bb; r.y += bb; r.z += bb; r.w += bb;
        *(float4*)&out[((size_t)b*256 + o0 + q)*1024 + m] = r;
    }
}

// ---------------------------------------------------------------------------
extern "C" void kernel_launch(void* const* d_in, const int* in_sizes, int n_in,
                              void* d_out, int out_size, void* d_ws, size_t ws_size,
                              hipStream_t stream)
{
    const float* seed_xyz      = (const float*)d_in[0];
    const float* seed_features = (const float*)d_in[1];
    const float* objectness    = (const float*)d_in[2];
    const float* graspness     = (const float*)d_in[3];
    const float* rot           = (const float*)d_in[4];
    const float* w1            = (const float*)d_in[5];
    const float* b1            = (const float*)d_in[6];
    const float* w2            = (const float*)d_in[7];
    const float* b2            = (const float*)d_in[8];
    const float* fw            = (const float*)d_in[9];
    const float* fb            = (const float*)d_in[10];
    float* out = (float*)d_out;

    char* ws = (char*)d_ws;
    size_t off = 0;
    int*   idxs   = (int*)(ws + off);  off += 16u<<10;            // 16 KB
    float* xyz_g  = (float*)(ws + off); off += 48u<<10;           // 48 KB
    float* feat_g = (float*)(ws + off); off += 8u<<20;            // 8 MB
    float* F1     = (float*)(ws + off); off += 16u<<20;           // 16 MB
    float* w2t    = (float*)(ws + off); off += 1u<<20;            // 1 MB
    float* w1x    = (float*)(ws + off); off += 64u<<10;           // 12 KB used
    int*   sel    = (int*)(ws + off);   off += 1u<<20;            // 1 MB
    int*   cnt    = (int*)(ws + off);   off += 64u<<10;           // 64 KB
    float* lxyz   = (float*)(ws + off); off += 3u<<20;            // 3 MB
    float* cat    = (float*)(ws + off); off += 16u<<20;           // 16 MB
    float* catT   = (float*)(ws + off); off += 16u<<20;           // 16 MB

    // FPS compaction scratch aliases `cat` (first written much later by k_mlp)
    float* xc = cat;
    float* yc = cat + 4*20480;
    float* zc = cat + 8*20480;
    int*   ci = (int*)(cat + 12*20480);

    k_fps<<<NB, 1024, 0, stream>>>(seed_xyz, objectness, graspness, idxs, xyz_g,
                                   xc, yc, zc, ci);
    k_prep<<<dim3(4,8,8), 256, 0, stream>>>(w1, w2, w2t, w1x);
    k_gather_feat<<<NB*MP, 256, 0, stream>>>(seed_features, idxs, feat_g);
    k_f1<<<dim3(64,4,4), 256, 0, stream>>>(feat_g, w1, b1, F1);
    k_nbr<<<NB*MP, 1024, 0, stream>>>(xyz_g, rot, sel, lxyz, cnt);
    k_mlp<<<4096, 256, 0, stream>>>(F1, w1x, w2t, b2, sel, lxyz, cnt, cat);
    k_transpose<<<4096, 256, 0, stream>>>(cat, catT);
    k_fuse<<<dim3(64,4), 256, 0, stream>>>(catT, fw, fb, out);
}